// Round 3
// baseline (724.596 us; speedup 1.0000x reference)
//
#include <hip/hip_runtime.h>

// Problem constants (n=8, c=64, h=w=256, points=8192)
#define NB    8
#define NC    64
#define HDIM  256
#define HW    65536        // 256*256
#define NPTS  8192
#define TOTPTS (NB*NPTS)   // 65536
#define N1    33554432     // 8*64*256*256 (x_out elements)

__device__ __forceinline__ int reflect_idx(int t) {
    t = t < 0 ? -t : t;
    return t > 255 ? 510 - t : t;
}

// ---------------------------------------------------------------------------
// Build winner map: map[n][ph*256+pw] = p (duplicate races benign: one
// winner survives; losers' work is simply never done).
// ---------------------------------------------------------------------------
__global__ __launch_bounds__(256) void scatter_map_kernel(
    const int* __restrict__ sfl, int* __restrict__ map)
{
    int p  = blockIdx.x * 256 + threadIdx.x;   // 0..65535
    int n  = p >> 13;
    int ph = sfl[2 * p];
    int pw = sfl[2 * p + 1];
    map[(n << 16) + (ph << 8) + pw] = p;
}

// ---------------------------------------------------------------------------
// Compact map -> position-ordered winner list. One entry per UNIQUE winner
// cell: wlist[i] = (n<<16)|pos. Ballot compaction: intra-wave order exact,
// cross-wave approx block order -> good spatial locality for attn gathers.
// ---------------------------------------------------------------------------
__global__ __launch_bounds__(256) void compact_kernel(
    const int* __restrict__ map, int* __restrict__ wlist,
    int* __restrict__ counter)
{
    int g = blockIdx.x * 256 + threadIdx.x;    // 0..524287 == (n<<16)|pos
    int lane = threadIdx.x & 63;
    bool pred = map[g] >= 0;
    unsigned long long mask = __ballot(pred);
    int base = 0;
    if (lane == 0) base = atomicAdd(counter, __popcll(mask));
    base = __shfl(base, 0);
    if (pred) {
        unsigned long long lt = mask & ((1ull << lane) - 1ull);
        wlist[base + __popcll(lt)] = g;
    }
}

// ---------------------------------------------------------------------------
// Pure streaming base pass: out = x1*(1+alpha). Grid-stride, 2 float4 in
// flight per thread. No LDS, no map — nothing to throttle it.
// ---------------------------------------------------------------------------
#define SCALE_GRID 2048
__global__ __launch_bounds__(256) void scale_v2_kernel(
    const float* __restrict__ x1, const float* __restrict__ alpha_p,
    float* __restrict__ out)
{
    const size_t N4 = N1 / 4;                       // 8388608 float4
    float sc = 1.0f + alpha_p[0];
    size_t i = (size_t)blockIdx.x * 256 + threadIdx.x;
    size_t stride = (size_t)SCALE_GRID * 256;       // 524288 -> 16 iters
    const float4* xv = (const float4*)x1;
    float4* ov = (float4*)out;
    for (size_t g = i; g < N4; g += 2 * stride) {
        float4 a = xv[g];
        float4 b = xv[g + stride];
        float4 oa = {a.x * sc, a.y * sc, a.z * sc, a.w * sc};
        float4 ob = {b.x * sc, b.y * sc, b.z * sc, b.w * sc};
        ov[g] = oa;
        ov[g + stride] = ob;
    }
}

// ---------------------------------------------------------------------------
// Winner-only attention, direct NCHW gather. One wave per winner cell,
// lane = channel. Per row: two aligned float4 loads cover the 5-col window
// (wave-uniform select); reflect slow path for boundary pw (~1.6%).
// xa stays in registers for the PV pass. Result scatter-written over the
// scaled base in out (one deterministic write per cell — no races).
// ---------------------------------------------------------------------------
__global__ __launch_bounds__(256) void attn_gather_kernel(
    const float* __restrict__ x1, const float* __restrict__ x2,
    const int* __restrict__ sfl_unused, const float* __restrict__ alpha_p,
    const int* __restrict__ wlist, const int* __restrict__ counter,
    float* __restrict__ out)
{
    int wid = blockIdx.x * 4 + (threadIdx.x >> 6);   // wave id = winner idx
    if (wid >= counter[0]) return;
    int lane = threadIdx.x & 63;                     // channel c
    int g = wlist[wid];
    int n = g >> 16;
    int pos = g & 0xFFFF;
    int ph = pos >> 8, pw = pos & 255;
    float alpha = alpha_p[0];

    size_t base = ((size_t)(n * NC + lane)) << 16;   // channel plane base
    float xp = x1[base + pos];

    int rh[5];
#pragma unroll
    for (int d = 0; d < 5; ++d) rh[d] = reflect_idx(ph + d - 2);

    const float* x2p = x2 + base;
    float xa[25];
    if (pw >= 2 && pw <= 253) {
        int a0 = (pw - 2) & ~3;
        int r  = (pw - 2) & 3;
#pragma unroll
        for (int i = 0; i < 5; ++i) {
            const float* rp = x2p + (rh[i] << 8) + a0;
            float4 lo = *(const float4*)rp;
            float4 hi = *(const float4*)(rp + 4);
            float v0, v1, v2, v3, v4;
            if (r == 0)      { v0=lo.x; v1=lo.y; v2=lo.z; v3=lo.w; v4=hi.x; }
            else if (r == 1) { v0=lo.y; v1=lo.z; v2=lo.w; v3=hi.x; v4=hi.y; }
            else if (r == 2) { v0=lo.z; v1=lo.w; v2=hi.x; v3=hi.y; v4=hi.z; }
            else             { v0=lo.w; v1=hi.x; v2=hi.y; v3=hi.z; v4=hi.w; }
            xa[i*5+0]=v0; xa[i*5+1]=v1; xa[i*5+2]=v2; xa[i*5+3]=v3; xa[i*5+4]=v4;
        }
    } else {
        int rw[5];
#pragma unroll
        for (int d = 0; d < 5; ++d) rw[d] = reflect_idx(pw + d - 2);
#pragma unroll
        for (int i = 0; i < 5; ++i)
#pragma unroll
            for (int j = 0; j < 5; ++j)
                xa[i*5+j] = x2p[(rh[i] << 8) + rw[j]];
    }

    // e[k] = sum_c xp[c]*xa[k][c]  (64-lane butterfly; result in all lanes)
    float e[25];
#pragma unroll
    for (int k = 0; k < 25; ++k) {
        float v = xp * xa[k];
        v += __shfl_xor(v, 1);  v += __shfl_xor(v, 2);  v += __shfl_xor(v, 4);
        v += __shfl_xor(v, 8);  v += __shfl_xor(v, 16); v += __shfl_xor(v, 32);
        e[k] = v;
    }
    float m = e[0];
#pragma unroll
    for (int k = 1; k < 25; ++k) m = fmaxf(m, e[k]);
    float s = 0.f;
#pragma unroll
    for (int k = 0; k < 25; ++k) { e[k] = __expf(e[k] - m); s += e[k]; }
    float inv = __frcp_rn(s);

    float f = 0.f;
#pragma unroll
    for (int k = 0; k < 25; ++k) f += e[k] * xa[k];

    out[base + pos] = xp + alpha * (f * inv);
}

// Fallback attention (tier C): per-point (dups compute identical values —
// benign race), NCHW gather, direct scatter over scaled base.
__global__ __launch_bounds__(256) void attn_fallback_kernel(
    const float* __restrict__ x1, const float* __restrict__ x2,
    const int* __restrict__ sfl, const float* __restrict__ alpha_p,
    float* __restrict__ out)
{
    int p    = (blockIdx.x << 2) + (threadIdx.x >> 6);
    int lane = threadIdx.x & 63;
    int n    = p >> 13;
    int ph   = sfl[2 * p];
    int pw   = sfl[2 * p + 1];
    float alpha = alpha_p[0];

    size_t x1idx = (((size_t)(n * NC + lane)) << 16) + (size_t)((ph << 8) + pw);
    float xp = x1[x1idx];

    float xa[25];
#pragma unroll
    for (int k = 0; k < 25; ++k) {
        int rh = reflect_idx(ph + k / 5 - 2);
        int rw = reflect_idx(pw + k % 5 - 2);
        xa[k] = x2[(((size_t)(n * NC + lane)) << 16) + (size_t)((rh << 8) + rw)];
    }
    float e[25];
#pragma unroll
    for (int k = 0; k < 25; ++k) {
        float v = xp * xa[k];
        v += __shfl_xor(v, 32); v += __shfl_xor(v, 16); v += __shfl_xor(v, 8);
        v += __shfl_xor(v, 4);  v += __shfl_xor(v, 2);  v += __shfl_xor(v, 1);
        e[k] = v;
    }
    float m = e[0];
#pragma unroll
    for (int k = 1; k < 25; ++k) m = fmaxf(m, e[k]);
    float s = 0.f;
#pragma unroll
    for (int k = 0; k < 25; ++k) { e[k] = __expf(e[k] - m); s += e[k]; }
    float inv = __frcp_rn(s);
    float f = 0.f;
#pragma unroll
    for (int k = 0; k < 25; ++k) f += e[k] * xa[k];
    out[x1idx] = xp + alpha * (f * inv);
}

__global__ __launch_bounds__(256) void tail_kernel(
    const int* __restrict__ sfl, float* __restrict__ outtail)
{
    int i = blockIdx.x * 256 + threadIdx.x;   // 0..131071
    outtail[i] = (float)sfl[i];
}

extern "C" void kernel_launch(void* const* d_in, const int* in_sizes, int n_in,
                              void* d_out, int out_size, void* d_ws, size_t ws_size,
                              hipStream_t stream)
{
    const float* x1    = (const float*)d_in[0];
    const float* x2    = (const float*)d_in[1];
    const int*   sfl   = (const int*)d_in[2];
    const float* alpha = (const float*)d_in[3];
    float* out = (float*)d_out;

    const size_t MAP_BYTES = (size_t)NB * HW * 4;        // 2,097,152
    const size_t CNT_BYTES = 256;
    const size_t WL_BYTES  = (size_t)TOTPTS * 4;         //   262,144

    if (ws_size >= MAP_BYTES + CNT_BYTES + WL_BYTES) {
        // Tier A: scale stream -> winner map -> compact -> gather-attn scatter
        int* map     = (int*)d_ws;
        int* counter = (int*)((char*)d_ws + MAP_BYTES);
        int* wlist   = (int*)((char*)d_ws + MAP_BYTES + CNT_BYTES);
        hipMemsetAsync(map, 0xFF, MAP_BYTES, stream);
        hipMemsetAsync(counter, 0, 4, stream);
        scale_v2_kernel<<<SCALE_GRID, 256, 0, stream>>>(x1, alpha, out);
        scatter_map_kernel<<<TOTPTS / 256, 256, 0, stream>>>(sfl, map);
        compact_kernel<<<(NB * HW) / 256, 256, 0, stream>>>(map, wlist, counter);
        attn_gather_kernel<<<TOTPTS / 4, 256, 0, stream>>>(
            x1, x2, sfl, alpha, wlist, counter, out);
        tail_kernel<<<(TOTPTS * 2) / 256, 256, 0, stream>>>(sfl, out + N1);
    } else {
        // Tier C: no workspace — base pass then direct scatter (dups benign)
        scale_v2_kernel<<<SCALE_GRID, 256, 0, stream>>>(x1, alpha, out);
        attn_fallback_kernel<<<TOTPTS / 4, 256, 0, stream>>>(
            x1, x2, sfl, alpha, out);
        tail_kernel<<<(TOTPTS * 2) / 256, 256, 0, stream>>>(sfl, out + N1);
    }
}

// Round 4
// 539.625 us; speedup vs baseline: 1.3428x; 1.3428x over previous
//
#include <hip/hip_runtime.h>

// Problem constants (n=8, c=64, h=w=256, points=8192)
#define NB    8
#define NC    64
#define HDIM  256
#define HW    65536        // 256*256
#define NPTS  8192
#define TOTPTS (NB*NPTS)   // 65536
#define N1    33554432     // 8*64*256*256 (x_out elements)

__device__ __forceinline__ int reflect_idx(int t) {
    t = t < 0 ? -t : t;
    return t > 255 ? 510 - t : t;
}

// ---------------------------------------------------------------------------
// Build winner map: map[n][ph*256+pw] = p (duplicate races benign: one
// winner survives per cell; duplicates compute identical values anyway).
// ---------------------------------------------------------------------------
__global__ __launch_bounds__(256) void scatter_map_kernel(
    const int* __restrict__ sfl, int* __restrict__ map)
{
    int p  = blockIdx.x * 256 + threadIdx.x;   // 0..65535
    int n  = p >> 13;
    int ph = sfl[2 * p];
    int pw = sfl[2 * p + 1];
    map[(n << 16) + (ph << 8) + pw] = p;
}

// ---------------------------------------------------------------------------
// Compact map -> dense winner list AND rewrite map in place to the winner
// INDEX (or -1). After this kernel:
//   wlist[i] = (n<<16)|pos  for i in [0,count)
//   map[g]   = i (dense index) if winner else -1
// so scale_extract's fus writes and attn_v5's fus reads use the SAME dense
// indexing — no unfilled reads possible (round-2 bug fixed structurally).
// ---------------------------------------------------------------------------
__global__ __launch_bounds__(256) void compact_kernel(
    int* __restrict__ map, int* __restrict__ wlist, int* __restrict__ counter)
{
    int g = blockIdx.x * 256 + threadIdx.x;    // 0..524287 == (n<<16)|pos
    int lane = threadIdx.x & 63;
    bool pred = map[g] >= 0;
    unsigned long long mask = __ballot(pred);
    int base = 0;
    if (lane == 0) base = atomicAdd(counter, __popcll(mask));
    base = __shfl(base, 0);
    int idx = -1;
    if (pred) {
        unsigned long long lt = mask & ((1ull << lane) - 1ull);
        idx = base + __popcll(lt);
        wlist[idx] = g;
    }
    map[g] = idx;
}

// ---------------------------------------------------------------------------
// Streaming pass over x1: out = x1*(1+alpha) (coalesced float4) AND extract
// RAW x1 winner rows (c-contiguous) into fus[winner_index] via one 64x65
// LDS tile (16.64 KB -> 8 blocks/CU). LDS write/read both 2-way = free.
// ---------------------------------------------------------------------------
__global__ __launch_bounds__(256) void scale_extract_kernel(
    const float* __restrict__ x1, const float* __restrict__ alpha_p,
    const int* __restrict__ map, float* __restrict__ out,
    float* __restrict__ fus)
{
    __shared__ float tB[64 * 65];
    int nb  = blockIdx.x;          // 0..8191  (8 n * 1024 tiles)
    int n   = nb >> 10;
    int hw0 = (nb & 1023) << 6;    // tile base in hw (64 rows)
    int t   = threadIdx.x;
    float sc = 1.0f + alpha_p[0];

    int u  = t & 15;               // hw quad index (hw_local = 4u + r)
    int cb = t >> 4;               // channel base 0..15
    const float* src1 = x1 + ((size_t)n << 22);   // n*64*65536
    float*       dst1 = out + ((size_t)n << 22);
    float4 vb[4];
#pragma unroll
    for (int i = 0; i < 4; ++i) {
        int c = cb + 16 * i;
        size_t gidx = ((size_t)c << 16) + (size_t)(hw0 + u * 4);
        vb[i] = *(const float4*)(src1 + gidx);
    }
#pragma unroll
    for (int i = 0; i < 4; ++i) {
        int c = cb + 16 * i;
        size_t gidx = ((size_t)c << 16) + (size_t)(hw0 + u * 4);
        float4 o = {vb[i].x * sc, vb[i].y * sc, vb[i].z * sc, vb[i].w * sc};
        *(float4*)(dst1 + gidx) = o;
#pragma unroll
        for (int r = 0; r < 4; ++r)
            tB[(u * 4 + r) * 65 + c] = (&vb[i].x)[r];
    }
    __syncthreads();

    // extract winner rows -> fus[widx] (coalesced 256B per winner)
    int uc = t & 15;               // c quad index (c = 4*uc + j)
    int rq = t >> 4;               // row base 0..3
#pragma unroll
    for (int i = 0; i < 4; ++i) {
        int row = rq + 16 * i;
        int wi = map[(n << 16) + hw0 + row];   // dense winner index or -1
        if (wi >= 0) {
            float4 g;
#pragma unroll
            for (int j = 0; j < 4; ++j) (&g.x)[j] = tB[row * 65 + uc * 4 + j];
            ((float4*)fus)[(size_t)wi * 16 + uc] = g;
        }
    }
}

// ---------------------------------------------------------------------------
// x2-only NCHW->NHWC transpose. Single 64x65 tile (16.64 KB) -> 8 blocks/CU.
// Launched immediately before attn so x2t is L2/L3-warm.
// ---------------------------------------------------------------------------
__global__ __launch_bounds__(256) void transpose_x2_v3(
    const float* __restrict__ x2, float* __restrict__ x2t)
{
    __shared__ float tA[64 * 65];
    int nb  = blockIdx.x;          // 0..8191
    int n   = nb >> 10;
    int hw0 = (nb & 1023) << 6;
    int t   = threadIdx.x;

    int u  = t & 15;
    int cb = t >> 4;
    const float* src2 = x2 + ((size_t)n << 22);
    float4 va[4];
#pragma unroll
    for (int i = 0; i < 4; ++i) {
        int c = cb + 16 * i;
        size_t gidx = ((size_t)c << 16) + (size_t)(hw0 + u * 4);
        va[i] = *(const float4*)(src2 + gidx);
    }
#pragma unroll
    for (int i = 0; i < 4; ++i) {
        int c = cb + 16 * i;
#pragma unroll
        for (int r = 0; r < 4; ++r)
            tA[(u * 4 + r) * 65 + c] = (&va[i].x)[r];
    }
    __syncthreads();

    int uc = t & 15;
    int rq = t >> 4;
    float4* dst = (float4*)(x2t + (((size_t)n << 16) + (size_t)hw0) * 64);
#pragma unroll
    for (int i = 0; i < 4; ++i) {
        int row = rq + 16 * i;
        float4 w;
#pragma unroll
        for (int j = 0; j < 4; ++j) (&w.x)[j] = tA[row * 65 + uc * 4 + j];
        dst[(size_t)row * 16 + uc] = w;
    }
}

// ---------------------------------------------------------------------------
// Attention v5: winner-only, online softmax (SINGLE x2t pass — halves the
// logical read volume vs the two-pass version that measured 111 us).
// 4 winners per wave, 16 lanes per winner, lane holds 4 channels (float4).
// xp from dense fus prefill; result scatter-written over scaled base in out
// (one deterministic write per cell — no races, no merge pass).
// ---------------------------------------------------------------------------
__global__ __launch_bounds__(256) void attn_v5_kernel(
    const float* __restrict__ x2t, const float* __restrict__ alpha_p,
    const int* __restrict__ wlist, const int* __restrict__ counter,
    const float* __restrict__ fus, float* __restrict__ out)
{
    int wid = blockIdx.x * 16 + (threadIdx.x >> 4);  // dense winner index
    if (wid >= counter[0]) return;
    int u = threadIdx.x & 15;                        // channel quad
    int g = wlist[wid];
    int n = g >> 16;
    int pos = g & 0xFFFF;
    int ph = pos >> 8, pw = pos & 255;
    float alpha = alpha_p[0];

    float4 xp = ((const float4*)fus)[(size_t)wid * 16 + u];

    int rh[5], rw[5];
#pragma unroll
    for (int d = 0; d < 5; ++d) {
        rh[d] = reflect_idx(ph + d - 2);
        rw[d] = reflect_idx(pw + d - 2);
    }
    const float4* x2v = (const float4*)x2t;
    size_t nbase = ((size_t)n << 16);

    // online softmax accumulation: m (running max), s (denom), f (numerator)
    float m = -1e30f, s = 0.f;
    float4 f = {0.f, 0.f, 0.f, 0.f};
#pragma unroll
    for (int k = 0; k < 25; ++k) {
        int i = k / 5, j = k % 5;
        size_t idx = (nbase + (size_t)((rh[i] << 8) + rw[j])) * 16 + u;
        float4 a = x2v[idx];
        float v = xp.x * a.x + xp.y * a.y + xp.z * a.z + xp.w * a.w;
        v += __shfl_xor(v, 1);
        v += __shfl_xor(v, 2);
        v += __shfl_xor(v, 4);
        v += __shfl_xor(v, 8);
        float mn   = fmaxf(m, v);
        float corr = __expf(m - mn);
        float p    = __expf(v - mn);
        s = s * corr + p;
        f.x = f.x * corr + p * a.x;
        f.y = f.y * corr + p * a.y;
        f.z = f.z * corr + p * a.z;
        f.w = f.w * corr + p * a.w;
        m = mn;
    }
    float inv = __frcp_rn(s);

    // scatter winner row into out (NCHW): channels 4u..4u+3, stride 65536
    float* outp = out + ((size_t)n << 22)
                      + ((size_t)(u << 2) << 16)
                      + (size_t)pos;
    outp[0]       = xp.x + alpha * (f.x * inv);
    outp[1 << 16] = xp.y + alpha * (f.y * inv);
    outp[2 << 16] = xp.z + alpha * (f.z * inv);
    outp[3 << 16] = xp.w + alpha * (f.w * inv);
}

// ---------------------------------------------------------------------------
// Tier C: pure streaming base pass out = x1*(1+alpha).
// ---------------------------------------------------------------------------
#define SCALE_GRID 2048
__global__ __launch_bounds__(256) void scale_v2_kernel(
    const float* __restrict__ x1, const float* __restrict__ alpha_p,
    float* __restrict__ out)
{
    const size_t N4 = N1 / 4;
    float sc = 1.0f + alpha_p[0];
    size_t i = (size_t)blockIdx.x * 256 + threadIdx.x;
    size_t stride = (size_t)SCALE_GRID * 256;
    const float4* xv = (const float4*)x1;
    float4* ov = (float4*)out;
    for (size_t g = i; g < N4; g += 2 * stride) {
        float4 a = xv[g];
        float4 b = xv[g + stride];
        float4 oa = {a.x * sc, a.y * sc, a.z * sc, a.w * sc};
        float4 ob = {b.x * sc, b.y * sc, b.z * sc, b.w * sc};
        ov[g] = oa;
        ov[g + stride] = ob;
    }
}

// Tier C fallback attention: per-point, NCHW gather, scatter over scaled base
// (duplicates write identical values — benign race).
__global__ __launch_bounds__(256) void attn_fallback_kernel(
    const float* __restrict__ x1, const float* __restrict__ x2,
    const int* __restrict__ sfl, const float* __restrict__ alpha_p,
    float* __restrict__ out)
{
    int p    = (blockIdx.x << 2) + (threadIdx.x >> 6);
    int lane = threadIdx.x & 63;
    int n    = p >> 13;
    int ph   = sfl[2 * p];
    int pw   = sfl[2 * p + 1];
    float alpha = alpha_p[0];

    size_t x1idx = (((size_t)(n * NC + lane)) << 16) + (size_t)((ph << 8) + pw);
    float xp = x1[x1idx];

    float xa[25];
#pragma unroll
    for (int k = 0; k < 25; ++k) {
        int rh = reflect_idx(ph + k / 5 - 2);
        int rw = reflect_idx(pw + k % 5 - 2);
        xa[k] = x2[(((size_t)(n * NC + lane)) << 16) + (size_t)((rh << 8) + rw)];
    }
    float e[25];
#pragma unroll
    for (int k = 0; k < 25; ++k) {
        float v = xp * xa[k];
        v += __shfl_xor(v, 32); v += __shfl_xor(v, 16); v += __shfl_xor(v, 8);
        v += __shfl_xor(v, 4);  v += __shfl_xor(v, 2);  v += __shfl_xor(v, 1);
        e[k] = v;
    }
    float m = e[0];
#pragma unroll
    for (int k = 1; k < 25; ++k) m = fmaxf(m, e[k]);
    float s = 0.f;
#pragma unroll
    for (int k = 0; k < 25; ++k) { e[k] = __expf(e[k] - m); s += e[k]; }
    float inv = __frcp_rn(s);
    float f = 0.f;
#pragma unroll
    for (int k = 0; k < 25; ++k) f += e[k] * xa[k];
    out[x1idx] = xp + alpha * (f * inv);
}

__global__ __launch_bounds__(256) void tail_kernel(
    const int* __restrict__ sfl, float* __restrict__ outtail)
{
    int i = blockIdx.x * 256 + threadIdx.x;   // 0..131071
    outtail[i] = (float)sfl[i];
}

extern "C" void kernel_launch(void* const* d_in, const int* in_sizes, int n_in,
                              void* d_out, int out_size, void* d_ws, size_t ws_size,
                              hipStream_t stream)
{
    const float* x1    = (const float*)d_in[0];
    const float* x2    = (const float*)d_in[1];
    const int*   sfl   = (const int*)d_in[2];
    const float* alpha = (const float*)d_in[3];
    float* out = (float*)d_out;

    const size_t X2T_BYTES = (size_t)NB * HW * NC * 4;   // 134,217,728
    const size_t FUS_BYTES = (size_t)TOTPTS * NC * 4;    //  16,777,216
    const size_t MAP_BYTES = (size_t)NB * HW * 4;        //   2,097,152
    const size_t WL_BYTES  = (size_t)TOTPTS * 4;         //     262,144
    const size_t CNT_BYTES = 256;

    if (ws_size >= X2T_BYTES + FUS_BYTES + MAP_BYTES + WL_BYTES + CNT_BYTES) {
        // Tier A: map -> compact(dense idx) -> scale+extract -> transpose
        //         -> winner-only online-softmax attn (scatter) -> tail
        float* x2t   = (float*)d_ws;
        float* fus   = (float*)((char*)d_ws + X2T_BYTES);
        int*   map   = (int*)((char*)d_ws + X2T_BYTES + FUS_BYTES);
        int*   wlist = (int*)((char*)d_ws + X2T_BYTES + FUS_BYTES + MAP_BYTES);
        int*   cnt   = (int*)((char*)d_ws + X2T_BYTES + FUS_BYTES + MAP_BYTES + WL_BYTES);
        hipMemsetAsync(map, 0xFF, MAP_BYTES, stream);
        hipMemsetAsync(cnt, 0, 4, stream);
        scatter_map_kernel<<<TOTPTS / 256, 256, 0, stream>>>(sfl, map);
        compact_kernel<<<(NB * HW) / 256, 256, 0, stream>>>(map, wlist, cnt);
        scale_extract_kernel<<<8192, 256, 0, stream>>>(x1, alpha, map, out, fus);
        transpose_x2_v3<<<8192, 256, 0, stream>>>(x2, x2t);
        attn_v5_kernel<<<TOTPTS / 16, 256, 0, stream>>>(x2t, alpha, wlist, cnt, fus, out);
        tail_kernel<<<(TOTPTS * 2) / 256, 256, 0, stream>>>(sfl, out + N1);
    } else {
        // Tier C: no workspace — base pass then direct scatter (dups benign)
        scale_v2_kernel<<<SCALE_GRID, 256, 0, stream>>>(x1, alpha, out);
        attn_fallback_kernel<<<TOTPTS / 4, 256, 0, stream>>>(
            x1, x2, sfl, alpha, out);
        tail_kernel<<<(TOTPTS * 2) / 256, 256, 0, stream>>>(sfl, out + N1);
    }
}

// Round 6
// 508.046 us; speedup vs baseline: 1.4262x; 1.0622x over previous
//
#include <hip/hip_runtime.h>

// Problem constants (n=8, c=64, h=w=256, points=8192)
#define NB    8
#define NC    64
#define HDIM  256
#define HW    65536        // 256*256
#define NPTS  8192
#define TOTPTS (NB*NPTS)   // 65536
#define N1    33554432     // 8*64*256*256 (x_out elements)

// clang ext vector: accepted by __builtin_nontemporal_* (HIP_vector_type is not)
typedef float f32x4 __attribute__((ext_vector_type(4)));

__device__ __forceinline__ int reflect_idx(int t) {
    t = t < 0 ? -t : t;
    return t > 255 ? 510 - t : t;
}

// ---------------------------------------------------------------------------
// Build winner map: map[n][ph*256+pw] = p. The winning point id p IS the
// winner index (p < 65536 == fus capacity) — no compaction kernel, no
// atomics. Duplicate races benign: one winner survives per cell.
// ---------------------------------------------------------------------------
__global__ __launch_bounds__(256) void scatter_map_kernel(
    const int* __restrict__ sfl, int* __restrict__ map)
{
    int p  = blockIdx.x * 256 + threadIdx.x;   // 0..65535
    int n  = p >> 13;
    int ph = sfl[2 * p];
    int pw = sfl[2 * p + 1];
    map[(n << 16) + (ph << 8) + pw] = p;
}

// ---------------------------------------------------------------------------
// Fused streaming pass, 16384 blocks:
//   blocks [0,8192):    out = x1*(1+alpha) (NT) + extract winner x1 rows
//                       (c-contiguous) into fus[winner_p] via 64x65 LDS tile
//   blocks [8192,16384): x2 NCHW->NHWC transpose into x2t (x2t NOT NT:
//                       attention re-reads it from L3)
// 16.64 KB LDS -> 8 blocks/CU. NT on single-use traffic (x1/x2 reads, out
// writes) preserves L3 for x2t.
// ---------------------------------------------------------------------------
__global__ __launch_bounds__(256) void stream_pass_kernel(
    const float* __restrict__ x1, const float* __restrict__ x2,
    const float* __restrict__ alpha_p, const int* __restrict__ map,
    float* __restrict__ out, float* __restrict__ fus,
    float* __restrict__ x2t)
{
    __shared__ float tile[64 * 65];
    int bid = blockIdx.x;
    int t   = threadIdx.x;
    int u   = t & 15;              // hw quad index (hw_local = 4u + r)
    int cb  = t >> 4;              // channel base 0..15
    int uc  = t & 15;              // c quad index (c = 4*uc + j)
    int rq  = t >> 4;              // row base 0..15

    if (bid < 8192) {
        // ---- scale + extract over x1 ----
        int n   = bid >> 10;
        int hw0 = (bid & 1023) << 6;
        float sc = 1.0f + alpha_p[0];
        const float* src1 = x1 + ((size_t)n << 22);
        float*       dst1 = out + ((size_t)n << 22);
        f32x4 vb[4];
#pragma unroll
        for (int i = 0; i < 4; ++i) {
            int c = cb + 16 * i;
            size_t gidx = ((size_t)c << 16) + (size_t)(hw0 + u * 4);
            vb[i] = __builtin_nontemporal_load((const f32x4*)(src1 + gidx));
        }
#pragma unroll
        for (int i = 0; i < 4; ++i) {
            int c = cb + 16 * i;
            size_t gidx = ((size_t)c << 16) + (size_t)(hw0 + u * 4);
            f32x4 o = vb[i] * sc;
            __builtin_nontemporal_store(o, (f32x4*)(dst1 + gidx));
#pragma unroll
            for (int r = 0; r < 4; ++r)
                tile[(u * 4 + r) * 65 + c] = vb[i][r];
        }
        __syncthreads();
#pragma unroll
        for (int i = 0; i < 4; ++i) {
            int row = rq + 16 * i;
            int wi = map[(n << 16) + hw0 + row];   // winner point id or -1
            if (wi >= 0) {
                f32x4 g;
#pragma unroll
                for (int j = 0; j < 4; ++j) g[j] = tile[row * 65 + uc * 4 + j];
                ((f32x4*)fus)[(size_t)wi * 16 + uc] = g;
            }
        }
    } else {
        // ---- x2 transpose ----
        int nb  = bid - 8192;
        int n   = nb >> 10;
        int hw0 = (nb & 1023) << 6;
        const float* src2 = x2 + ((size_t)n << 22);
        f32x4 va[4];
#pragma unroll
        for (int i = 0; i < 4; ++i) {
            int c = cb + 16 * i;
            size_t gidx = ((size_t)c << 16) + (size_t)(hw0 + u * 4);
            va[i] = __builtin_nontemporal_load((const f32x4*)(src2 + gidx));
        }
#pragma unroll
        for (int i = 0; i < 4; ++i) {
            int c = cb + 16 * i;
#pragma unroll
            for (int r = 0; r < 4; ++r)
                tile[(u * 4 + r) * 65 + c] = va[i][r];
        }
        __syncthreads();
        f32x4* dst = (f32x4*)(x2t + (((size_t)n << 16) + (size_t)hw0) * 64);
#pragma unroll
        for (int i = 0; i < 4; ++i) {
            int row = rq + 16 * i;
            f32x4 w;
#pragma unroll
            for (int j = 0; j < 4; ++j) w[j] = tile[row * 65 + uc * 4 + j];
            dst[(size_t)row * 16 + uc] = w;    // reused by attn: keep cached
        }
    }
}

// ---------------------------------------------------------------------------
// Attention v6: cell-ordered winner-only online-softmax attention.
// 8192 blocks x 16 groups (16 lanes each) x 4 cells: block b covers 64
// consecutive cells -> position-order locality without any compaction.
// XCD-chunked swizzle (8192%8==0, bijective): each XCD owns a contiguous
// cell range (~one batch) -> x2t rows reused in its L2, scatter-write
// sectors merge in L2. Early exit on map[g]<0 (~88% of groups).
// xp from fus[winner_p]; result NT-scattered over scaled base in out.
// ---------------------------------------------------------------------------
__global__ __launch_bounds__(256) void attn_v6_kernel(
    const float* __restrict__ x2t, const float* __restrict__ alpha_p,
    const int* __restrict__ map, const float* __restrict__ fus,
    float* __restrict__ out)
{
    int bid = blockIdx.x;
    int swz = ((bid & 7) << 10) + (bid >> 3);        // XCD-chunked, bijective
    int grp = threadIdx.x >> 4;                      // 0..15
    int u   = threadIdx.x & 15;                      // channel quad
    float alpha = alpha_p[0];
    int cellbase = swz << 6;                         // 64 cells per block

    const f32x4* x2v = (const f32x4*)x2t;

#pragma unroll 1
    for (int gi = 0; gi < 4; ++gi) {
        int g = cellbase + gi * 16 + grp;            // cell id = (n<<16)|pos
        int p = map[g];
        if (p < 0) continue;
        int n   = g >> 16;
        int pos = g & 0xFFFF;
        int ph  = pos >> 8, pw = pos & 255;

        f32x4 xp = ((const f32x4*)fus)[(size_t)p * 16 + u];

        int rh[5], rw[5];
#pragma unroll
        for (int d = 0; d < 5; ++d) {
            rh[d] = reflect_idx(ph + d - 2);
            rw[d] = reflect_idx(pw + d - 2);
        }
        size_t nbase = ((size_t)n << 16);

        float m = -1e30f, s = 0.f;
        f32x4 f = {0.f, 0.f, 0.f, 0.f};
#pragma unroll
        for (int k = 0; k < 25; ++k) {
            int i = k / 5, j = k % 5;
            size_t idx = (nbase + (size_t)((rh[i] << 8) + rw[j])) * 16 + u;
            f32x4 a = x2v[idx];
            float v = xp.x * a.x + xp.y * a.y + xp.z * a.z + xp.w * a.w;
            v += __shfl_xor(v, 1);
            v += __shfl_xor(v, 2);
            v += __shfl_xor(v, 4);
            v += __shfl_xor(v, 8);
            float mn   = fmaxf(m, v);
            float corr = __expf(m - mn);
            float pe   = __expf(v - mn);
            s = s * corr + pe;
            f = f * corr + a * pe;
            m = mn;
        }
        float inv = __frcp_rn(s);

        float* outp = out + ((size_t)n << 22)
                          + ((size_t)(u << 2) << 16)
                          + (size_t)pos;
        __builtin_nontemporal_store(xp.x + alpha * (f.x * inv), outp);
        __builtin_nontemporal_store(xp.y + alpha * (f.y * inv), outp + (1 << 16));
        __builtin_nontemporal_store(xp.z + alpha * (f.z * inv), outp + (2 << 16));
        __builtin_nontemporal_store(xp.w + alpha * (f.w * inv), outp + (3 << 16));
    }
}

// ---------------------------------------------------------------------------
// Tier C: pure streaming base pass out = x1*(1+alpha).
// ---------------------------------------------------------------------------
#define SCALE_GRID 2048
__global__ __launch_bounds__(256) void scale_v2_kernel(
    const float* __restrict__ x1, const float* __restrict__ alpha_p,
    float* __restrict__ out)
{
    const size_t N4 = N1 / 4;
    float sc = 1.0f + alpha_p[0];
    size_t i = (size_t)blockIdx.x * 256 + threadIdx.x;
    size_t stride = (size_t)SCALE_GRID * 256;
    const float4* xv = (const float4*)x1;
    float4* ov = (float4*)out;
    for (size_t g = i; g < N4; g += 2 * stride) {
        float4 a = xv[g];
        float4 b = xv[g + stride];
        float4 oa = {a.x * sc, a.y * sc, a.z * sc, a.w * sc};
        float4 ob = {b.x * sc, b.y * sc, b.z * sc, b.w * sc};
        ov[g] = oa;
        ov[g + stride] = ob;
    }
}

// Tier C fallback attention: per-point, NCHW gather, scatter over scaled base
// (duplicates write identical values — benign race).
__global__ __launch_bounds__(256) void attn_fallback_kernel(
    const float* __restrict__ x1, const float* __restrict__ x2,
    const int* __restrict__ sfl, const float* __restrict__ alpha_p,
    float* __restrict__ out)
{
    int p    = (blockIdx.x << 2) + (threadIdx.x >> 6);
    int lane = threadIdx.x & 63;
    int n    = p >> 13;
    int ph   = sfl[2 * p];
    int pw   = sfl[2 * p + 1];
    float alpha = alpha_p[0];

    size_t x1idx = (((size_t)(n * NC + lane)) << 16) + (size_t)((ph << 8) + pw);
    float xp = x1[x1idx];

    float xa[25];
#pragma unroll
    for (int k = 0; k < 25; ++k) {
        int rh = reflect_idx(ph + k / 5 - 2);
        int rw = reflect_idx(pw + k % 5 - 2);
        xa[k] = x2[(((size_t)(n * NC + lane)) << 16) + (size_t)((rh << 8) + rw)];
    }
    float e[25];
#pragma unroll
    for (int k = 0; k < 25; ++k) {
        float v = xp * xa[k];
        v += __shfl_xor(v, 32); v += __shfl_xor(v, 16); v += __shfl_xor(v, 8);
        v += __shfl_xor(v, 4);  v += __shfl_xor(v, 2);  v += __shfl_xor(v, 1);
        e[k] = v;
    }
    float m = e[0];
#pragma unroll
    for (int k = 1; k < 25; ++k) m = fmaxf(m, e[k]);
    float s = 0.f;
#pragma unroll
    for (int k = 0; k < 25; ++k) { e[k] = __expf(e[k] - m); s += e[k]; }
    float inv = __frcp_rn(s);
    float f = 0.f;
#pragma unroll
    for (int k = 0; k < 25; ++k) f += e[k] * xa[k];
    out[x1idx] = xp + alpha * (f * inv);
}

__global__ __launch_bounds__(256) void tail_kernel(
    const int* __restrict__ sfl, float* __restrict__ outtail)
{
    int i = blockIdx.x * 256 + threadIdx.x;   // 0..131071
    outtail[i] = (float)sfl[i];
}

extern "C" void kernel_launch(void* const* d_in, const int* in_sizes, int n_in,
                              void* d_out, int out_size, void* d_ws, size_t ws_size,
                              hipStream_t stream)
{
    const float* x1    = (const float*)d_in[0];
    const float* x2    = (const float*)d_in[1];
    const int*   sfl   = (const int*)d_in[2];
    const float* alpha = (const float*)d_in[3];
    float* out = (float*)d_out;

    const size_t X2T_BYTES = (size_t)NB * HW * NC * 4;   // 134,217,728
    const size_t FUS_BYTES = (size_t)TOTPTS * NC * 4;    //  16,777,216
    const size_t MAP_BYTES = (size_t)NB * HW * 4;        //   2,097,152

    if (ws_size >= X2T_BYTES + FUS_BYTES + MAP_BYTES) {
        // Tier A: map -> fused stream pass (scale+extract | transpose)
        //         -> cell-ordered winner attn (scatter) -> tail
        float* x2t = (float*)d_ws;
        float* fus = (float*)((char*)d_ws + X2T_BYTES);
        int*   map = (int*)((char*)d_ws + X2T_BYTES + FUS_BYTES);
        (void)hipMemsetAsync(map, 0xFF, MAP_BYTES, stream);
        scatter_map_kernel<<<TOTPTS / 256, 256, 0, stream>>>(sfl, map);
        stream_pass_kernel<<<16384, 256, 0, stream>>>(
            x1, x2, alpha, map, out, fus, x2t);
        attn_v6_kernel<<<8192, 256, 0, stream>>>(x2t, alpha, map, fus, out);
        tail_kernel<<<(TOTPTS * 2) / 256, 256, 0, stream>>>(sfl, out + N1);
    } else {
        // Tier C: no workspace — base pass then direct scatter (dups benign)
        scale_v2_kernel<<<SCALE_GRID, 256, 0, stream>>>(x1, alpha, out);
        attn_fallback_kernel<<<TOTPTS / 4, 256, 0, stream>>>(
            x1, x2, sfl, alpha, out);
        tail_kernel<<<(TOTPTS * 2) / 256, 256, 0, stream>>>(sfl, out + N1);
    }
}